// Round 2
// baseline (2842.183 us; speedup 1.0000x reference)
//
#include <hip/hip_runtime.h>
#include <math.h>
#include <limits.h>

#define NEV 100000
#define NB 8
#define F32EPS 1.1920929e-7f

// ws layout (floats):
//   grids: per (b, mask, dir): 87040 cells x 2 (num,den interleaved) = 174080 floats
//     region base = b*696320 + mask*348160 + dir*174080
//     within region: fiOff2 = {0, 2048, 10240, 43008} + (y*W + x)*2   (+0 num, +1 den)
//   total grids = 5,570,560 floats = 22,282,240 bytes
//   tref: 32 floats at float offset 5,570,560
#define GRID_FLOATS 5570560
#define REGION 174080
#define MASK_STRIDE 348160
#define B_STRIDE 696320

// ---------------- t_ref per (batch, polarity, dir) + zero out ----------------
__global__ __launch_bounds__(1024) void k_tref(const int* __restrict__ ps,
                                               const float* __restrict__ ts,
                                               float* __restrict__ tref,
                                               float* __restrict__ out) {
    int b = blockIdx.x;
    if (b == 0 && threadIdx.x == 0) out[0] = 0.0f;
    const int* p = ps + b * NEV;
    int mnP = INT_MAX, mxP = -1, mnN = INT_MAX, mxN = -1;
    for (int i = threadIdx.x; i < NEV; i += blockDim.x) {
        int v = p[i];
        if (v == 1) { mnP = min(mnP, i); mxP = max(mxP, i); }
        else        { mnN = min(mnN, i); mxN = max(mxN, i); }
    }
    for (int o = 32; o > 0; o >>= 1) {
        mnP = min(mnP, __shfl_down(mnP, o, 64));
        mxP = max(mxP, __shfl_down(mxP, o, 64));
        mnN = min(mnN, __shfl_down(mnN, o, 64));
        mxN = max(mxN, __shfl_down(mxN, o, 64));
    }
    __shared__ int s[4];
    if (threadIdx.x == 0) { s[0] = INT_MAX; s[1] = -1; s[2] = INT_MAX; s[3] = -1; }
    __syncthreads();
    if ((threadIdx.x & 63) == 0) {
        atomicMin(&s[0], mnP); atomicMax(&s[1], mxP);
        atomicMin(&s[2], mnN); atomicMax(&s[3], mxN);
    }
    __syncthreads();
    if (threadIdx.x == 0) {
        const float* t = ts + b * NEV;
        int fP = (s[0] == INT_MAX) ? 0 : s[0];
        int lP = (s[1] < 0) ? (NEV - 1) : s[1];
        int fN = (s[2] == INT_MAX) ? 0 : s[2];
        int lN = (s[3] < 0) ? (NEV - 1) : s[3];
        tref[b * 4 + 0] = t[lP];  // pos fwd
        tref[b * 4 + 1] = t[fP];  // pos bwd
        tref[b * 4 + 2] = t[lN];  // neg fwd
        tref[b * 4 + 3] = t[fN];  // neg bwd
    }
}

// ---------------- event splat: each event read ONCE, global atomics ----------------
__global__ __launch_bounds__(256) void k_splat_g(
    const float* __restrict__ f0, const float* __restrict__ f1,
    const float* __restrict__ f2, const float* __restrict__ f3,
    const int* __restrict__ xs, const int* __restrict__ ys,
    const float* __restrict__ ts, const int* __restrict__ ps,
    const float* __restrict__ tref, float* __restrict__ grids) {
    int b = blockIdx.x & 7;          // batch -> XCD affinity
    int slice = blockIdx.x >> 3;
    int stride = (gridDim.x >> 3) * blockDim.x;

    const int*   xb = xs + b * NEV;
    const int*   yb = ys + b * NEV;
    const float* tb = ts + b * NEV;
    const int*   pb = ps + b * NEV;

    float tr0F = tref[b * 4 + 0], tr0B = tref[b * 4 + 1];
    float tr1F = tref[b * 4 + 2], tr1B = tref[b * 4 + 3];

    const float* fpl[4] = { f0 + b * 2048, f1 + b * 8192,
                            f2 + b * 32768, f3 + b * 131072 };
    const int fiOff2[4] = { 0, 2048, 10240, 43008 };
    float* gb = grids + (size_t)b * B_STRIDE;

    for (int i = slice * blockDim.x + threadIdx.x; i < NEV; i += stride) {
        int   p = pb[i];
        int   x = xb[i];
        int   y = yb[i];
        float t = tb[i];
        int mask = (p == 1) ? 0 : 1;
        float tF = ((mask == 0) ? tr0F : tr1F) - t + F32EPS;
        float tB = ((mask == 0) ? tr0B : tr1B) - t - F32EPS;
        float* r0 = gb + mask * MASK_STRIDE;

        #pragma unroll
        for (int fi = 0; fi < 4; ++fi) {
            const int sh = 3 - fi;
            const int W = 32 << fi;
            const float Wm1 = (float)(W - 1);
            int xi = x >> sh, yi = y >> sh;
            const float* fp = fpl[fi];
            float fx = fp[yi * W + xi];
            float fy = fp[W * W + yi * W + xi];
            float* g0 = r0 + fiOff2[fi];
            #pragma unroll
            for (int dir = 0; dir < 2; ++dir) {
                float t_ = dir ? tB : tF;
                float* g = g0 + dir * REGION;
                float x_ = fminf(fmaxf((float)xi + t_ * fx, 0.0f), Wm1);
                float y_ = fminf(fmaxf((float)yi + t_ * fy, 0.0f), Wm1);
                float x0f = floorf(x_), y0f = floorf(y_);
                float x0w = x_ - x0f, x1w = 1.0f - x0w;
                float y0w = y_ - y0f, y1w = 1.0f - y0w;
                int x0i = (int)x0f, y0i = (int)y0f;
                int x1i = min(x0i + 1, W - 1);
                int y1i = min(y0i + 1, W - 1);
                float Ta = x0w * y0w * t;   // -> (x1i, y1i)
                float Tb_ = x1w * y0w * t;  // -> (x0i, y1i)
                float Tc = x0w * y1w * t;   // -> (x1i, y0i)
                float Td = x1w * y1w * t;   // -> (x0i, y0i)
                int ca = (y1i * W + x1i) * 2;
                int cb = (y1i * W + x0i) * 2;
                int cc = (y0i * W + x1i) * 2;
                int cd = (y0i * W + x0i) * 2;
                atomicAdd(&g[ca], Ta);  atomicAdd(&g[ca + 1], 1.0f);
                atomicAdd(&g[cb], Tb_); atomicAdd(&g[cb + 1], 1.0f);
                atomicAdd(&g[cc], Tc);  atomicAdd(&g[cc + 1], 1.0f);
                atomicAdd(&g[cd], Td);  atomicAdd(&g[cd + 1], 1.0f);
            }
        }
    }
}

// ---------------- reduce grids -> sum sqrt((num/(den+eps))^2 + 1e-6) ----------------
__global__ __launch_bounds__(256) void k_reduce(const float* __restrict__ grids,
                                                float* __restrict__ out) {
    const int nPairs = GRID_FLOATS / 2;  // 2,785,280
    const float2* g2 = (const float2*)grids;
    float s = 0.0f;
    for (int i = blockIdx.x * blockDim.x + threadIdx.x; i < nPairs;
         i += gridDim.x * blockDim.x) {
        float2 v = g2[i];
        float r = v.x / (v.y + F32EPS);
        s += sqrtf(r * r + 1e-6f);
    }
    for (int o = 32; o > 0; o >>= 1) s += __shfl_down(s, o, 64);
    __shared__ float red[4];
    if ((threadIdx.x & 63) == 0) red[threadIdx.x >> 6] = s;
    __syncthreads();
    if (threadIdx.x == 0) {
        float tot = red[0] + red[1] + red[2] + red[3];
        atomicAdd(out, tot);
    }
}

// ---------------- weight decay: sum(p^2) * 5e-5 ----------------
__global__ __launch_bounds__(256) void k_wd(const float* __restrict__ p, int n,
                                            float* __restrict__ out) {
    float s = 0.0f;
    int n4 = n >> 2;
    const float4* p4 = (const float4*)p;
    for (int i = blockIdx.x * blockDim.x + threadIdx.x; i < n4;
         i += gridDim.x * blockDim.x) {
        float4 v = p4[i];
        s += v.x * v.x + v.y * v.y + v.z * v.z + v.w * v.w;
    }
    if (blockIdx.x == 0 && threadIdx.x == 0) {
        for (int i = n4 * 4; i < n; ++i) s += p[i] * p[i];
    }
    for (int o = 32; o > 0; o >>= 1) s += __shfl_down(s, o, 64);
    __shared__ float red[4];
    if ((threadIdx.x & 63) == 0) red[threadIdx.x >> 6] = s;
    __syncthreads();
    if (threadIdx.x == 0)
        atomicAdd(out, (red[0] + red[1] + red[2] + red[3]) * 5e-5f);
}

// ---------------- smoothness, all 4 flows in one kernel ----------------
// per-fi element counts: 16*W*W; cumulative: 16384, 81920, 344064, 1392640
__global__ __launch_bounds__(256) void k_smooth_all(
    const float* __restrict__ f0, const float* __restrict__ f1,
    const float* __restrict__ f2, const float* __restrict__ f3,
    float* __restrict__ out) {
    const int nTot = 1392640;
    float s = 0.0f;
    for (int idx = blockIdx.x * blockDim.x + threadIdx.x; idx < nTot;
         idx += gridDim.x * blockDim.x) {
        int fi, off, logW;
        if (idx < 16384)       { fi = 0; off = 0;      logW = 5; }
        else if (idx < 81920)  { fi = 1; off = 16384;  logW = 6; }
        else if (idx < 344064) { fi = 2; off = 81920;  logW = 7; }
        else                   { fi = 3; off = 344064; logW = 8; }
        const float* f = (fi == 0) ? f0 : (fi == 1) ? f1 : (fi == 2) ? f2 : f3;
        int W = 1 << logW;
        int local = idx - off;
        int x = local & (W - 1);
        int y = (local >> logW) & (W - 1);
        float c_lr = 6.25f / (float)(16 * W * (W - 1));
        float c_dd = 6.25f / (float)(16 * (W - 1) * (W - 1));
        float v = f[local];
        bool xok = x < W - 1;
        bool yok = y < W - 1;
        float vr = xok ? f[local + 1] : 0.0f;
        float vd = yok ? f[local + W] : 0.0f;
        if (xok) { float d = vr - v; s += c_lr * __powf(d * d + 1e-6f, 0.45f); }
        if (yok) { float d = vd - v; s += c_lr * __powf(d * d + 1e-6f, 0.45f); }
        if (xok && yok) {
            float d1 = f[local + W + 1] - v;
            s += c_dd * __powf(d1 * d1 + 1e-6f, 0.45f);
            float d2 = vr - vd;
            s += c_dd * __powf(d2 * d2 + 1e-6f, 0.45f);
        }
    }
    for (int o = 32; o > 0; o >>= 1) s += __shfl_down(s, o, 64);
    __shared__ float red[4];
    if ((threadIdx.x & 63) == 0) red[threadIdx.x >> 6] = s;
    __syncthreads();
    if (threadIdx.x == 0)
        atomicAdd(out, red[0] + red[1] + red[2] + red[3]);
}

extern "C" void kernel_launch(void* const* d_in, const int* in_sizes, int n_in,
                              void* d_out, int out_size, void* d_ws, size_t ws_size,
                              hipStream_t stream) {
    const float* f0 = (const float*)d_in[0];
    const float* f1 = (const float*)d_in[1];
    const float* f2 = (const float*)d_in[2];
    const float* f3 = (const float*)d_in[3];
    const int*   xs = (const int*)d_in[4];
    const int*   ys = (const int*)d_in[5];
    const float* ts = (const float*)d_in[6];
    const int*   ps = (const int*)d_in[7];
    const float* params = (const float*)d_in[10];
    float* out   = (float*)d_out;
    float* grids = (float*)d_ws;
    float* tref  = grids + GRID_FLOATS;

    hipMemsetAsync(d_ws, 0, (size_t)GRID_FLOATS * 4, stream);
    hipLaunchKernelGGL(k_tref, dim3(NB), dim3(1024), 0, stream, ps, ts, tref, out);
    hipLaunchKernelGGL(k_splat_g, dim3(768), dim3(256), 0, stream,
                       f0, f1, f2, f3, xs, ys, ts, ps, tref, grids);
    hipLaunchKernelGGL(k_wd, dim3(512), dim3(256), 0, stream, params, in_sizes[10], out);
    hipLaunchKernelGGL(k_smooth_all, dim3(512), dim3(256), 0, stream, f0, f1, f2, f3, out);
    hipLaunchKernelGGL(k_reduce, dim3(1024), dim3(256), 0, stream, grids, out);
}

// Round 3
// 1322.954 us; speedup vs baseline: 2.1484x; 2.1484x over previous
//
#include <hip/hip_runtime.h>
#include <math.h>
#include <limits.h>

#define NEV 100000
#define NB 8
#define F32EPS 1.1920929e-7f

// ws layout (bytes):
//   [0, 6,400,000)              uint2 bins[8][NEV]   (x | y<<8, float bits of t)
//   [6,400,000, +8*33*4)        int binStart[8][33]  (cumulative, per batch)
//   then                        float tref[32]
#define BINS_BYTES (NB * NEV * 8)

// =============== binning + tref + zero-out (one block per batch) ===============
__global__ __launch_bounds__(1024) void k_bin(
    const int* __restrict__ xs, const int* __restrict__ ys,
    const float* __restrict__ ts, const int* __restrict__ ps,
    uint2* __restrict__ bins, int* __restrict__ binStart,
    float* __restrict__ tref, float* __restrict__ out) {
    int b = blockIdx.x;
    int tid = threadIdx.x;
    if (b == 0 && tid == 0) out[0] = 0.0f;

    const int*   xb = xs + b * NEV;
    const int*   yb = ys + b * NEV;
    const float* tb = ts + b * NEV;
    const int*   pb = ps + b * NEV;

    __shared__ int hist[32];
    __shared__ int cur[32];
    __shared__ int mm[4];
    if (tid < 32) hist[tid] = 0;
    if (tid == 0) { mm[0] = INT_MAX; mm[1] = -1; mm[2] = INT_MAX; mm[3] = -1; }
    __syncthreads();

    int mnP = INT_MAX, mxP = -1, mnN = INT_MAX, mxN = -1;
    for (int i = tid; i < NEV; i += 1024) {
        int p = pb[i];
        int y = yb[i];
        int m = (p == 1) ? 0 : 1;
        atomicAdd(&hist[m * 16 + (y >> 4)], 1);
        if (m == 0) { mnP = min(mnP, i); mxP = max(mxP, i); }
        else        { mnN = min(mnN, i); mxN = max(mxN, i); }
    }
    for (int o = 32; o > 0; o >>= 1) {
        mnP = min(mnP, __shfl_down(mnP, o, 64));
        mxP = max(mxP, __shfl_down(mxP, o, 64));
        mnN = min(mnN, __shfl_down(mnN, o, 64));
        mxN = max(mxN, __shfl_down(mxN, o, 64));
    }
    if ((tid & 63) == 0) {
        atomicMin(&mm[0], mnP); atomicMax(&mm[1], mxP);
        atomicMin(&mm[2], mnN); atomicMax(&mm[3], mxN);
    }
    __syncthreads();
    if (tid == 0) {
        int acc = 0;
        for (int k = 0; k < 32; ++k) {
            cur[k] = acc;
            binStart[b * 33 + k] = acc;
            acc += hist[k];
        }
        binStart[b * 33 + 32] = acc;  // == NEV
        int fP = (mm[0] == INT_MAX) ? 0 : mm[0];
        int lP = (mm[1] < 0) ? (NEV - 1) : mm[1];
        int fN = (mm[2] == INT_MAX) ? 0 : mm[2];
        int lN = (mm[3] < 0) ? (NEV - 1) : mm[3];
        tref[b * 4 + 0] = tb[lP];  // pos fwd
        tref[b * 4 + 1] = tb[fP];  // pos bwd
        tref[b * 4 + 2] = tb[lN];  // neg fwd
        tref[b * 4 + 3] = tb[fN];  // neg bwd
    }
    __syncthreads();
    for (int i = tid; i < NEV; i += 1024) {
        int p = pb[i];
        int x = xb[i];
        int y = yb[i];
        float t = tb[i];
        int m = (p == 1) ? 0 : 1;
        int pos = atomicAdd(&cur[m * 16 + (y >> 4)], 1);
        bins[b * NEV + pos] = make_uint2((unsigned)(x | (y << 8)), __float_as_uint(t));
    }
}

// =============== event splat into LDS dest-chunk grids + in-block reduce ===============
// 368 blocks: b = bid&7 (XCD affinity), rm = bid>>3 (0..45): mask = rm&1, role = rm>>1 (0..22)
//  role 0      : fi0 whole grid (32 rows),  bins 0..15
//  role 1..2   : fi1 chunk c, 32 rows,      bins max(0,8c-2)..min(15,8c+9)   (halo 8 fi-rows)
//  role 3..6   : fi2 chunk c, 32 rows,      bins max(0,4c-1)..min(15,4c+4)   (halo 8 fi-rows)
//  role 7..22  : fi3 chunk c, 16 rows,      bins max(0,c-1)..min(15,c+1)     (halo 16 fi-rows)
// max displacement in data: |t_|*|fy| <= ~5.3 fi-rows < all halos.
// LDS: dir d: num at d*2*planeN, den at d*2*planeN + planeN; planeN <= 4096.
__global__ __launch_bounds__(1024) void k_splat(
    const float* __restrict__ f0, const float* __restrict__ f1,
    const float* __restrict__ f2, const float* __restrict__ f3,
    const uint2* __restrict__ bins, const int* __restrict__ binStart,
    const float* __restrict__ tref, float* __restrict__ out) {
    __shared__ float acc[16384];  // 64 KB

    int bid = blockIdx.x;
    int b = bid & 7;
    int rm = bid >> 3;
    int mask = rm & 1;
    int role = rm >> 1;

    int fi, row0, nrows, lo, hi;
    if (role == 0)      { fi = 0; row0 = 0; nrows = 32; lo = 0; hi = 15; }
    else if (role < 3)  { int c = role - 1; fi = 1; row0 = 32 * c; nrows = 32;
                          lo = max(0, 8 * c - 2); hi = min(15, 8 * c + 9); }
    else if (role < 7)  { int c = role - 3; fi = 2; row0 = 32 * c; nrows = 32;
                          lo = max(0, 4 * c - 1); hi = min(15, 4 * c + 4); }
    else                { int c = role - 7; fi = 3; row0 = 16 * c; nrows = 16;
                          lo = max(0, c - 1); hi = min(15, c + 1); }

    int W = 32 << fi;
    int sh = 3 - fi;
    int planeN = nrows * W;        // 1024 / 2048 / 4096 / 4096
    int half = 2 * planeN;
    int rowEnd = row0 + nrows;
    float Wm1 = (float)(W - 1);

    const float* flow = (fi == 0) ? f0 : (fi == 1) ? f1 : (fi == 2) ? f2 : f3;
    const float* fxp = flow + (size_t)b * 2 * W * W;
    const float* fyp = fxp + W * W;

    int nInit = 4 * planeN;
    for (int i = threadIdx.x; i < nInit; i += 1024) acc[i] = 0.0f;
    __syncthreads();

    float trF = tref[b * 4 + mask * 2 + 0];
    float trB = tref[b * 4 + mask * 2 + 1];

    int s0 = binStart[b * 33 + mask * 16 + lo];
    int e0 = binStart[b * 33 + mask * 16 + hi + 1];
    const uint2* eb = bins + b * NEV;

    for (int i = s0 + threadIdx.x; i < e0; i += 1024) {
        uint2 ev = eb[i];
        int x = ev.x & 255;
        int y = (ev.x >> 8) & 255;
        float t = __uint_as_float(ev.y);
        int xi = x >> sh, yi = y >> sh;
        float fx = fxp[yi * W + xi];
        float fy = fyp[yi * W + xi];
        float tF = trF - t + F32EPS;
        float tB = trB - t - F32EPS;
        #pragma unroll
        for (int dir = 0; dir < 2; ++dir) {
            float t_ = dir ? tB : tF;
            float x_ = fminf(fmaxf((float)xi + t_ * fx, 0.0f), Wm1);
            float y_ = fminf(fmaxf((float)yi + t_ * fy, 0.0f), Wm1);
            float x0f = floorf(x_), y0f = floorf(y_);
            float x0w = x_ - x0f, x1w = 1.0f - x0w;
            float y0w = y_ - y0f, y1w = 1.0f - y0w;
            int x0i = (int)x0f, y0i = (int)y0f;
            int x1i = min(x0i + 1, W - 1);
            int y1i = min(y0i + 1, W - 1);
            float Ta = x0w * y0w * t;   // -> (x1i, y1i)
            float Tb_ = x1w * y0w * t;  // -> (x0i, y1i)
            float Tc = x0w * y1w * t;   // -> (x1i, y0i)
            float Td = x1w * y1w * t;   // -> (x0i, y0i)
            float* num = acc + dir * half;
            float* den = num + planeN;
            if (y1i >= row0 && y1i < rowEnd) {
                int r = (y1i - row0) * W;
                atomicAdd(&num[r + x1i], Ta);  atomicAdd(&den[r + x1i], 1.0f);
                atomicAdd(&num[r + x0i], Tb_); atomicAdd(&den[r + x0i], 1.0f);
            }
            if (y0i >= row0 && y0i < rowEnd) {
                int r = (y0i - row0) * W;
                atomicAdd(&num[r + x1i], Tc);  atomicAdd(&den[r + x1i], 1.0f);
                atomicAdd(&num[r + x0i], Td);  atomicAdd(&den[r + x0i], 1.0f);
            }
        }
    }
    __syncthreads();

    float s = 0.0f;
    for (int off = threadIdx.x; off < planeN; off += 1024) {
        #pragma unroll
        for (int dir = 0; dir < 2; ++dir) {
            float num = acc[dir * half + off];
            float den = acc[dir * half + planeN + off];
            float r = num / (den + F32EPS);
            s += sqrtf(r * r + 1e-6f);
        }
    }
    for (int o = 32; o > 0; o >>= 1) s += __shfl_down(s, o, 64);
    __syncthreads();
    if ((threadIdx.x & 63) == 0) acc[threadIdx.x >> 6] = s;
    __syncthreads();
    if (threadIdx.x == 0) {
        float tot = 0.0f;
        for (int w = 0; w < 16; ++w) tot += acc[w];
        atomicAdd(out, tot);
    }
}

// =============== weight decay + smoothness, fused ===============
__global__ __launch_bounds__(256) void k_misc(
    const float* __restrict__ params, int nP,
    const float* __restrict__ f0, const float* __restrict__ f1,
    const float* __restrict__ f2, const float* __restrict__ f3,
    float* __restrict__ out) {
    float s = 0.0f;
    int gstride = gridDim.x * blockDim.x;
    int gtid = blockIdx.x * blockDim.x + threadIdx.x;

    // weight decay: sum(p^2) * 5e-5
    int n4 = nP >> 2;
    const float4* p4 = (const float4*)params;
    float w = 0.0f;
    for (int i = gtid; i < n4; i += gstride) {
        float4 v = p4[i];
        w += v.x * v.x + v.y * v.y + v.z * v.z + v.w * v.w;
    }
    if (gtid == 0) for (int i = n4 * 4; i < nP; ++i) w += params[i] * params[i];
    s += w * 5e-5f;

    // smoothness: 6.25 * (mean_lr + mean_ud + mean_d1 + mean_d2) per flow
    const int nTot = 1392640;
    for (int idx = gtid; idx < nTot; idx += gstride) {
        int fi, off, logW;
        if (idx < 16384)       { fi = 0; off = 0;      logW = 5; }
        else if (idx < 81920)  { fi = 1; off = 16384;  logW = 6; }
        else if (idx < 344064) { fi = 2; off = 81920;  logW = 7; }
        else                   { fi = 3; off = 344064; logW = 8; }
        const float* f = (fi == 0) ? f0 : (fi == 1) ? f1 : (fi == 2) ? f2 : f3;
        int W = 1 << logW;
        int local = idx - off;
        int x = local & (W - 1);
        int y = (local >> logW) & (W - 1);
        float c_lr = 6.25f / (float)(16 * W * (W - 1));
        float c_dd = 6.25f / (float)(16 * (W - 1) * (W - 1));
        float v = f[local];
        bool xok = x < W - 1;
        bool yok = y < W - 1;
        float vr = xok ? f[local + 1] : 0.0f;
        float vd = yok ? f[local + W] : 0.0f;
        if (xok) { float d = vr - v; s += c_lr * __powf(d * d + 1e-6f, 0.45f); }
        if (yok) { float d = vd - v; s += c_lr * __powf(d * d + 1e-6f, 0.45f); }
        if (xok && yok) {
            float d1 = f[local + W + 1] - v;
            s += c_dd * __powf(d1 * d1 + 1e-6f, 0.45f);
            float d2 = vr - vd;
            s += c_dd * __powf(d2 * d2 + 1e-6f, 0.45f);
        }
    }

    for (int o = 32; o > 0; o >>= 1) s += __shfl_down(s, o, 64);
    __shared__ float red[4];
    if ((threadIdx.x & 63) == 0) red[threadIdx.x >> 6] = s;
    __syncthreads();
    if (threadIdx.x == 0)
        atomicAdd(out, red[0] + red[1] + red[2] + red[3]);
}

extern "C" void kernel_launch(void* const* d_in, const int* in_sizes, int n_in,
                              void* d_out, int out_size, void* d_ws, size_t ws_size,
                              hipStream_t stream) {
    const float* f0 = (const float*)d_in[0];
    const float* f1 = (const float*)d_in[1];
    const float* f2 = (const float*)d_in[2];
    const float* f3 = (const float*)d_in[3];
    const int*   xs = (const int*)d_in[4];
    const int*   ys = (const int*)d_in[5];
    const float* ts = (const float*)d_in[6];
    const int*   ps = (const int*)d_in[7];
    const float* params = (const float*)d_in[10];
    float* out = (float*)d_out;

    char* ws = (char*)d_ws;
    uint2* bins    = (uint2*)ws;
    int*   binStart = (int*)(ws + BINS_BYTES);
    float* tref    = (float*)(ws + BINS_BYTES + NB * 33 * 4);

    hipLaunchKernelGGL(k_bin, dim3(NB), dim3(1024), 0, stream,
                       xs, ys, ts, ps, bins, binStart, tref, out);
    hipLaunchKernelGGL(k_splat, dim3(368), dim3(1024), 0, stream,
                       f0, f1, f2, f3, bins, binStart, tref, out);
    hipLaunchKernelGGL(k_misc, dim3(1024), dim3(256), 0, stream,
                       params, in_sizes[10], f0, f1, f2, f3, out);
}

// Round 4
// 274.019 us; speedup vs baseline: 10.3722x; 4.8280x over previous
//
#include <hip/hip_runtime.h>
#include <math.h>
#include <limits.h>

#define NEV 100000
#define NB 8
#define F32EPS 1.1920929e-7f
#define SCALE 524288.0f          // 2^19 fixed-point for num
#define INV_SCALE (1.0f/524288.0f)

typedef unsigned long long u64;

// ws layout (bytes):
//   [0, 6,400,000)    uint2 bins[8][NEV]     (x | y<<8, float bits of t)
//   +1056             int binStart[8][33]
//   +128              float tref[32]
//   fi0Part: u64[16][8][2048]   (2 MB)   at BINS_BYTES+1184
//   fi1Part: u64[16][4][8192]   (4 MB)
#define BINS_BYTES (NB * NEV * 8)
#define META_BYTES (NB * 33 * 4 + 128)

__device__ __forceinline__ void lds_add(u64* p, u64 v) {
    __hip_atomic_fetch_add(p, v, __ATOMIC_RELAXED, __HIP_MEMORY_SCOPE_WORKGROUP);
}

// =============== binning + tref + zero-out (one block per batch) ===============
__global__ __launch_bounds__(1024) void k_bin(
    const int* __restrict__ xs, const int* __restrict__ ys,
    const float* __restrict__ ts, const int* __restrict__ ps,
    uint2* __restrict__ bins, int* __restrict__ binStart,
    float* __restrict__ tref, float* __restrict__ out) {
    int b = blockIdx.x;
    int tid = threadIdx.x;
    int w = tid >> 6;
    if (b == 0 && tid == 0) out[0] = 0.0f;

    const int*   xb = xs + b * NEV;
    const int*   yb = ys + b * NEV;
    const float* tb = ts + b * NEV;
    const int*   pb = ps + b * NEV;

    __shared__ int hist[16][32];
    __shared__ int cur[16][32];
    __shared__ int startS[32];
    __shared__ int mm[4];
    if (tid < 512) hist[tid >> 5][tid & 31] = 0;
    if (tid == 0) { mm[0] = INT_MAX; mm[1] = -1; mm[2] = INT_MAX; mm[3] = -1; }
    __syncthreads();

    int mnP = INT_MAX, mxP = -1, mnN = INT_MAX, mxN = -1;
    for (int i = tid; i < NEV; i += 1024) {
        int p = pb[i];
        int y = yb[i];
        int m = (p == 1) ? 0 : 1;
        __hip_atomic_fetch_add(&hist[w][m * 16 + (y >> 4)], 1,
                               __ATOMIC_RELAXED, __HIP_MEMORY_SCOPE_WORKGROUP);
        if (m == 0) { mnP = min(mnP, i); mxP = max(mxP, i); }
        else        { mnN = min(mnN, i); mxN = max(mxN, i); }
    }
    for (int o = 32; o > 0; o >>= 1) {
        mnP = min(mnP, __shfl_down(mnP, o, 64));
        mxP = max(mxP, __shfl_down(mxP, o, 64));
        mnN = min(mnN, __shfl_down(mnN, o, 64));
        mxN = max(mxN, __shfl_down(mxN, o, 64));
    }
    if ((tid & 63) == 0) {
        atomicMin(&mm[0], mnP); atomicMax(&mm[1], mxP);
        atomicMin(&mm[2], mnN); atomicMax(&mm[3], mxN);
    }
    __syncthreads();
    if (tid < 32) {  // per-bin: exclusive prefix over waves
        int acc = 0;
        for (int w2 = 0; w2 < 16; ++w2) { int h = hist[w2][tid]; cur[w2][tid] = acc; acc += h; }
        startS[tid] = acc;  // total per bin
    }
    __syncthreads();
    if (tid == 0) {
        int run = 0;
        for (int k = 0; k < 32; ++k) {
            int t = startS[k];
            startS[k] = run;
            binStart[b * 33 + k] = run;
            run += t;
        }
        binStart[b * 33 + 32] = run;
        int fP = (mm[0] == INT_MAX) ? 0 : mm[0];
        int lP = (mm[1] < 0) ? (NEV - 1) : mm[1];
        int fN = (mm[2] == INT_MAX) ? 0 : mm[2];
        int lN = (mm[3] < 0) ? (NEV - 1) : mm[3];
        tref[b * 4 + 0] = tb[lP];  // pos fwd
        tref[b * 4 + 1] = tb[fP];  // pos bwd
        tref[b * 4 + 2] = tb[lN];  // neg fwd
        tref[b * 4 + 3] = tb[fN];  // neg bwd
    }
    __syncthreads();
    if (tid < 512) cur[tid >> 5][tid & 31] += startS[tid & 31];
    __syncthreads();
    for (int i = tid; i < NEV; i += 1024) {
        int p = pb[i];
        int x = xb[i];
        int y = yb[i];
        float t = tb[i];
        int m = (p == 1) ? 0 : 1;
        int bin = m * 16 + (y >> 4);
        int pos = __hip_atomic_fetch_add(&cur[w][bin], 1,
                                         __ATOMIC_RELAXED, __HIP_MEMORY_SCOPE_WORKGROUP);
        bins[b * NEV + pos] = make_uint2((unsigned)(x | (y << 8)), __float_as_uint(t));
    }
}

// =============== event splat ===============
// 576 blocks: b=bid&7, rm=bid>>3 (0..71): m=rm&1, role=rm>>1 (0..35)
//   role 0..7  : fi0, event-slice s (of 8), full 32x32 grid, 4 LDS replicas -> partial to ws
//   role 8..11 : fi1, event-slice s (of 4), full 64x64 grid              -> partial to ws
//   role 12..19: fi2 chunk c (16 rows of 128), bins 2c-1..2c+2, in-block finalize
//   role 20..35: fi3 chunk c (16 rows of 256), bins c-1..c+1,  in-block finalize
__global__ __launch_bounds__(1024) void k_splat(
    const float* __restrict__ f0, const float* __restrict__ f1,
    const float* __restrict__ f2, const float* __restrict__ f3,
    const uint2* __restrict__ bins, const int* __restrict__ binStart,
    const float* __restrict__ tref,
    u64* __restrict__ fi0P, u64* __restrict__ fi1P,
    float* __restrict__ out) {
    __shared__ u64 acc[8192];   // 64 KB
    __shared__ float red[16];

    int tid = threadIdx.x;
    int bid = blockIdx.x;
    int b = bid & 7;
    int rm = bid >> 3;
    int m = rm & 1;
    int role = rm >> 1;
    int bm = b * 2 + m;

    int fi, row0 = 0, nrows, lo, hi, slice = 0, nslice = 1, mode;
    if (role < 8)       { fi = 0; mode = 0; slice = role;      nslice = 8; nrows = 32; lo = 0; hi = 15; }
    else if (role < 12) { fi = 1; mode = 0; slice = role - 8;  nslice = 4; nrows = 64; lo = 0; hi = 15; }
    else if (role < 20) { int c = role - 12; fi = 2; mode = 1; row0 = 16 * c; nrows = 16;
                          lo = max(0, 2 * c - 1); hi = min(15, 2 * c + 2); }
    else                { int c = role - 20; fi = 3; mode = 1; row0 = 16 * c; nrows = 16;
                          lo = max(0, c - 1); hi = min(15, c + 1); }

    int W = 32 << fi;
    int sh = 3 - fi;
    int planeN = (fi == 0) ? 1024 : (fi == 1) ? 4096 : nrows * W;  // fi2:2048 fi3:4096
    int used = (fi == 0) ? 8192 : 2 * planeN;
    int rowEnd = row0 + nrows;
    float Wm1 = (float)(W - 1);

    const float* flow = (fi == 0) ? f0 : (fi == 1) ? f1 : (fi == 2) ? f2 : f3;
    const float* fxp = flow + (size_t)b * 2 * W * W;
    const float* fyp = fxp + W * W;

    for (int i = tid; i < used; i += 1024) acc[i] = 0ULL;
    __syncthreads();

    float trF = tref[b * 4 + m * 2 + 0];
    float trB = tref[b * 4 + m * 2 + 1];

    int s0 = binStart[b * 33 + m * 16 + lo];
    int e0 = binStart[b * 33 + m * 16 + hi + 1];
    const uint2* eb = bins + b * NEV;

    int rep = (fi == 0) ? (((tid >> 4) & 3) * 2048) : 0;

    for (int i = s0 + slice * 1024 + tid; i < e0; i += nslice * 1024) {
        uint2 ev = eb[i];
        int x = ev.x & 255;
        int y = (ev.x >> 8) & 255;
        float t = __uint_as_float(ev.y);
        int xi = x >> sh, yi = y >> sh;
        float fx = fxp[yi * W + xi];
        float fy = fyp[yi * W + xi];
        float tF = trF - t + F32EPS;
        float tB = trB - t - F32EPS;
        #pragma unroll
        for (int dir = 0; dir < 2; ++dir) {
            float t_ = dir ? tB : tF;
            float x_ = fminf(fmaxf((float)xi + t_ * fx, 0.0f), Wm1);
            float y_ = fminf(fmaxf((float)yi + t_ * fy, 0.0f), Wm1);
            float x0f = floorf(x_), y0f = floorf(y_);
            float x0w = x_ - x0f, x1w = 1.0f - x0w;
            float y0w = y_ - y0f, y1w = 1.0f - y0w;
            int x0i = (int)x0f, y0i = (int)y0f;
            int x1i = min(x0i + 1, W - 1);
            int y1i = min(y0i + 1, W - 1);
            // pack: den(+1) in high 32, num fixed-point in low 32
            u64 Pa = (1ULL << 32) | (u64)(unsigned)(x0w * y0w * t * SCALE);  // -> (x1i,y1i)
            u64 Pb = (1ULL << 32) | (u64)(unsigned)(x1w * y0w * t * SCALE);  // -> (x0i,y1i)
            u64 Pc = (1ULL << 32) | (u64)(unsigned)(x0w * y1w * t * SCALE);  // -> (x1i,y0i)
            u64 Pd = (1ULL << 32) | (u64)(unsigned)(x1w * y1w * t * SCALE);  // -> (x0i,y0i)
            int base = rep + dir * planeN;
            if (mode == 0) {
                int r1 = base + y1i * W;
                int r0 = base + y0i * W;
                lds_add(&acc[r1 + x1i], Pa);
                lds_add(&acc[r1 + x0i], Pb);
                lds_add(&acc[r0 + x1i], Pc);
                lds_add(&acc[r0 + x0i], Pd);
            } else {
                if (y1i >= row0 && y1i < rowEnd) {
                    int r = base + (y1i - row0) * W;
                    lds_add(&acc[r + x1i], Pa);
                    lds_add(&acc[r + x0i], Pb);
                }
                if (y0i >= row0 && y0i < rowEnd) {
                    int r = base + (y0i - row0) * W;
                    lds_add(&acc[r + x1i], Pc);
                    lds_add(&acc[r + x0i], Pd);
                }
            }
        }
    }
    __syncthreads();

    if (mode == 0) {
        if (fi == 0) {
            for (int j = tid; j < 2048; j += 1024)
                fi0P[(bm * 8 + slice) * 2048 + j] =
                    acc[j] + acc[j + 2048] + acc[j + 4096] + acc[j + 6144];
        } else {
            for (int j = tid; j < 8192; j += 1024)
                fi1P[(bm * 4 + slice) * 8192 + j] = acc[j];
        }
        return;
    }

    // mode 1: finalize chunk to scalar
    float s = 0.0f;
    for (int j = tid; j < used; j += 1024) {
        u64 v = acc[j];
        float num = (float)(unsigned)(v & 0xffffffffULL) * INV_SCALE;
        float den = (float)(unsigned)(v >> 32);
        float r = num / (den + F32EPS);
        s += sqrtf(r * r + 1e-6f);
    }
    for (int o = 32; o > 0; o >>= 1) s += __shfl_down(s, o, 64);
    if ((tid & 63) == 0) red[tid >> 6] = s;
    __syncthreads();
    if (tid == 0) {
        float tot = 0.0f;
        for (int w2 = 0; w2 < 16; ++w2) tot += red[w2];
        atomicAdd(out, tot);
    }
}

// =============== merge fi0/fi1 partials -> loss terms ===============
__global__ __launch_bounds__(256) void k_merge(const u64* __restrict__ fi0P,
                                               const u64* __restrict__ fi1P,
                                               float* __restrict__ out) {
    int idx = blockIdx.x * 256 + threadIdx.x;   // < 163840
    u64 v = 0;
    if (idx < 32768) {
        int bm = idx >> 11, j = idx & 2047;
        const u64* p = fi0P + (bm * 8) * 2048 + j;
        #pragma unroll
        for (int s = 0; s < 8; ++s) v += p[s * 2048];
    } else {
        int r = idx - 32768;
        int bm = r >> 13, j = r & 8191;
        const u64* p = fi1P + (bm * 4) * 8192 + j;
        #pragma unroll
        for (int s = 0; s < 4; ++s) v += p[s * 8192];
    }
    float num = (float)(unsigned)(v & 0xffffffffULL) * INV_SCALE;
    float den = (float)(unsigned)(v >> 32);
    float r = num / (den + F32EPS);
    float s = sqrtf(r * r + 1e-6f);
    for (int o = 32; o > 0; o >>= 1) s += __shfl_down(s, o, 64);
    __shared__ float red[4];
    if ((threadIdx.x & 63) == 0) red[threadIdx.x >> 6] = s;
    __syncthreads();
    if (threadIdx.x == 0)
        atomicAdd(out, red[0] + red[1] + red[2] + red[3]);
}

// =============== weight decay + smoothness ===============
__global__ __launch_bounds__(256) void k_misc(
    const float* __restrict__ params, int nP,
    const float* __restrict__ f0, const float* __restrict__ f1,
    const float* __restrict__ f2, const float* __restrict__ f3,
    float* __restrict__ out) {
    float s = 0.0f;
    int gstride = gridDim.x * blockDim.x;
    int gtid = blockIdx.x * blockDim.x + threadIdx.x;

    int n4 = nP >> 2;
    const float4* p4 = (const float4*)params;
    float w = 0.0f;
    for (int i = gtid; i < n4; i += gstride) {
        float4 v = p4[i];
        w += v.x * v.x + v.y * v.y + v.z * v.z + v.w * v.w;
    }
    if (gtid == 0) for (int i = n4 * 4; i < nP; ++i) w += params[i] * params[i];
    s += w * 5e-5f;

    const int nTot = 1392640;
    for (int idx = gtid; idx < nTot; idx += gstride) {
        int fi, off, logW;
        if (idx < 16384)       { fi = 0; off = 0;      logW = 5; }
        else if (idx < 81920)  { fi = 1; off = 16384;  logW = 6; }
        else if (idx < 344064) { fi = 2; off = 81920;  logW = 7; }
        else                   { fi = 3; off = 344064; logW = 8; }
        const float* f = (fi == 0) ? f0 : (fi == 1) ? f1 : (fi == 2) ? f2 : f3;
        int W = 1 << logW;
        int local = idx - off;
        int x = local & (W - 1);
        int y = (local >> logW) & (W - 1);
        float c_lr = 6.25f / (float)(16 * W * (W - 1));
        float c_dd = 6.25f / (float)(16 * (W - 1) * (W - 1));
        float v = f[local];
        bool xok = x < W - 1;
        bool yok = y < W - 1;
        float vr = xok ? f[local + 1] : 0.0f;
        float vd = yok ? f[local + W] : 0.0f;
        if (xok) { float d = vr - v; s += c_lr * __powf(d * d + 1e-6f, 0.45f); }
        if (yok) { float d = vd - v; s += c_lr * __powf(d * d + 1e-6f, 0.45f); }
        if (xok && yok) {
            float d1 = f[local + W + 1] - v;
            s += c_dd * __powf(d1 * d1 + 1e-6f, 0.45f);
            float d2 = vr - vd;
            s += c_dd * __powf(d2 * d2 + 1e-6f, 0.45f);
        }
    }

    for (int o = 32; o > 0; o >>= 1) s += __shfl_down(s, o, 64);
    __shared__ float red[4];
    if ((threadIdx.x & 63) == 0) red[threadIdx.x >> 6] = s;
    __syncthreads();
    if (threadIdx.x == 0)
        atomicAdd(out, red[0] + red[1] + red[2] + red[3]);
}

extern "C" void kernel_launch(void* const* d_in, const int* in_sizes, int n_in,
                              void* d_out, int out_size, void* d_ws, size_t ws_size,
                              hipStream_t stream) {
    const float* f0 = (const float*)d_in[0];
    const float* f1 = (const float*)d_in[1];
    const float* f2 = (const float*)d_in[2];
    const float* f3 = (const float*)d_in[3];
    const int*   xs = (const int*)d_in[4];
    const int*   ys = (const int*)d_in[5];
    const float* ts = (const float*)d_in[6];
    const int*   ps = (const int*)d_in[7];
    const float* params = (const float*)d_in[10];
    float* out = (float*)d_out;

    char* ws = (char*)d_ws;
    uint2* bins     = (uint2*)ws;
    int*   binStart = (int*)(ws + BINS_BYTES);
    float* tref     = (float*)(ws + BINS_BYTES + NB * 33 * 4);
    u64*   fi0P     = (u64*)(ws + BINS_BYTES + META_BYTES);
    u64*   fi1P     = fi0P + 16 * 8 * 2048;

    hipLaunchKernelGGL(k_bin, dim3(NB), dim3(1024), 0, stream,
                       xs, ys, ts, ps, bins, binStart, tref, out);
    hipLaunchKernelGGL(k_splat, dim3(576), dim3(1024), 0, stream,
                       f0, f1, f2, f3, bins, binStart, tref, fi0P, fi1P, out);
    hipLaunchKernelGGL(k_merge, dim3(640), dim3(256), 0, stream, fi0P, fi1P, out);
    hipLaunchKernelGGL(k_misc, dim3(1024), dim3(256), 0, stream,
                       params, in_sizes[10], f0, f1, f2, f3, out);
}

// Round 5
// 186.062 us; speedup vs baseline: 15.2755x; 1.4727x over previous
//
#include <hip/hip_runtime.h>
#include <math.h>
#include <limits.h>

#define NEV 100000
#define NB 8
#define NSL 32                   // slices per batch
#define SLEV (NEV / NSL)         // 3125 events per slice
#define F32EPS 1.1920929e-7f
#define SCALE 524288.0f          // 2^19 fixed-point for num
#define INV_SCALE (1.0f/524288.0f)

typedef unsigned long long u64;

// ws layout (bytes):
//   0          bins: uint2[8][NEV]                 6,400,000
//   6,400,000  binStart: int[8][33]                1,056
//   6,401,056  tref: float[32]                     128
//   6,401,184  fi0P: u64[16][8][2048]              2,097,152
//   8,498,336  fi1P: u64[16][4][8192]              4,194,304
//   12,692,640 histG: int[256][4][32]              131,072
//   12,823,712 cursG: int[256][4][32]              131,072
//   12,954,784 mmG:   int[256][4]                  4,096
#define BINS_BYTES 6400000
#define OFF_BINSTART 6400000
#define OFF_TREF     6401056
#define OFF_FI0P     6401184
#define OFF_FI1P     8498336
#define OFF_HISTG    12692640
#define OFF_CURSG    12823712
#define OFF_MMG      12954784

__device__ __forceinline__ void lds_add64(u64* p, u64 v) {
    __hip_atomic_fetch_add(p, v, __ATOMIC_RELAXED, __HIP_MEMORY_SCOPE_WORKGROUP);
}
__device__ __forceinline__ int lds_add32(int* p, int v) {
    return __hip_atomic_fetch_add(p, v, __ATOMIC_RELAXED, __HIP_MEMORY_SCOPE_WORKGROUP);
}

// =============== pass 1: per-(slice,wave) histograms + per-slice minmax ===============
// 256 blocks x 256 threads; bid = sl*8 + b  (b = bid&7 for XCD affinity)
__global__ __launch_bounds__(256) void k_hist(
    const int* __restrict__ ys, const int* __restrict__ ps,
    int* __restrict__ histG, int* __restrict__ mmG) {
    int bid = blockIdx.x;
    int b = bid & 7;
    int sl = bid >> 3;
    int tid = threadIdx.x;
    int w = tid >> 6, lane = tid & 63;

    const int* yb = ys + b * NEV + sl * SLEV;
    const int* pb = ps + b * NEV + sl * SLEV;

    __shared__ int hist[4][32];
    __shared__ int mm[4];
    if (tid < 128) hist[tid >> 5][tid & 31] = 0;
    if (tid == 0) { mm[0] = INT_MAX; mm[1] = -1; mm[2] = INT_MAX; mm[3] = -1; }
    __syncthreads();

    int mnP = INT_MAX, mxP = -1, mnN = INT_MAX, mxN = -1;
    int gbase = sl * SLEV;
    for (int i = w * 64 + lane; i < SLEV; i += 256) {
        int p = pb[i];
        int y = yb[i];
        int m = (p == 1) ? 0 : 1;
        lds_add32(&hist[w][m * 16 + (y >> 4)], 1);
        int gi = gbase + i;
        if (m == 0) { mnP = min(mnP, gi); mxP = max(mxP, gi); }
        else        { mnN = min(mnN, gi); mxN = max(mxN, gi); }
    }
    for (int o = 32; o > 0; o >>= 1) {
        mnP = min(mnP, __shfl_down(mnP, o, 64));
        mxP = max(mxP, __shfl_down(mxP, o, 64));
        mnN = min(mnN, __shfl_down(mnN, o, 64));
        mxN = max(mxN, __shfl_down(mxN, o, 64));
    }
    if (lane == 0) {
        atomicMin(&mm[0], mnP); atomicMax(&mm[1], mxP);
        atomicMin(&mm[2], mnN); atomicMax(&mm[3], mxN);
    }
    __syncthreads();
    if (tid < 128) histG[(bid * 4 + (tid >> 5)) * 32 + (tid & 31)] = hist[tid >> 5][tid & 31];
    if (tid < 4)   mmG[bid * 4 + tid] = mm[tid];
}

// =============== pass 2: hierarchical prefix + tref + zero out (1 block) ===============
__global__ __launch_bounds__(256) void k_scan(
    const int* __restrict__ histG, const int* __restrict__ mmG,
    const float* __restrict__ ts,
    int* __restrict__ cursG, int* __restrict__ binStart,
    float* __restrict__ tref, float* __restrict__ out) {
    int tid = threadIdx.x;
    int b = tid >> 5, bin = tid & 31;      // 256 threads = 8 x 32 pairs
    __shared__ int tot[8][32];
    __shared__ int bs[8][33];

    // per-(b,bin) total over 32 slices x 4 waves
    int s = 0;
    for (int sl = 0; sl < NSL; ++sl) {
        int bid = sl * 8 + b;
        #pragma unroll
        for (int w = 0; w < 4; ++w) s += histG[(bid * 4 + w) * 32 + bin];
    }
    tot[b][bin] = s;
    __syncthreads();

    if (tid < 8) {   // bin prefix per batch
        int run = 0;
        for (int k = 0; k < 32; ++k) { bs[tid][k] = run; run += tot[tid][k]; }
        bs[tid][32] = run;
    }
    __syncthreads();
    if (bin == 0 && b == 0) out[0] = 0.0f;
    // write binStart
    binStart[b * 33 + bin] = bs[b][bin];
    if (tid < 8) binStart[tid * 33 + 32] = bs[tid][32];

    // per-(slice,wave) exclusive prefix -> cursG
    int run = bs[b][bin];
    for (int sl = 0; sl < NSL; ++sl) {
        int bid = sl * 8 + b;
        #pragma unroll
        for (int w = 0; w < 4; ++w) {
            int idx = (bid * 4 + w) * 32 + bin;
            int h = histG[idx];
            cursG[idx] = run;
            run += h;
        }
    }

    // tref from mmG
    if (tid < 8) {
        int mnP = INT_MAX, mxP = -1, mnN = INT_MAX, mxN = -1;
        for (int sl = 0; sl < NSL; ++sl) {
            const int* m = mmG + (sl * 8 + tid) * 4;
            mnP = min(mnP, m[0]); mxP = max(mxP, m[1]);
            mnN = min(mnN, m[2]); mxN = max(mxN, m[3]);
        }
        const float* tb = ts + tid * NEV;
        int fP = (mnP == INT_MAX) ? 0 : mnP;
        int lP = (mxP < 0) ? (NEV - 1) : mxP;
        int fN = (mnN == INT_MAX) ? 0 : mnN;
        int lN = (mxN < 0) ? (NEV - 1) : mxN;
        tref[tid * 4 + 0] = tb[lP];  // pos fwd
        tref[tid * 4 + 1] = tb[fP];  // pos bwd
        tref[tid * 4 + 2] = tb[lN];  // neg fwd
        tref[tid * 4 + 3] = tb[fN];  // neg bwd
    }
}

// =============== pass 3: scatter into bins using exact per-wave cursors ===============
__global__ __launch_bounds__(256) void k_scatter(
    const int* __restrict__ xs, const int* __restrict__ ys,
    const float* __restrict__ ts, const int* __restrict__ ps,
    const int* __restrict__ cursG, uint2* __restrict__ bins) {
    int bid = blockIdx.x;
    int b = bid & 7;
    int sl = bid >> 3;
    int tid = threadIdx.x;
    int w = tid >> 6, lane = tid & 63;

    const int*   xb = xs + b * NEV + sl * SLEV;
    const int*   yb = ys + b * NEV + sl * SLEV;
    const float* tb = ts + b * NEV + sl * SLEV;
    const int*   pb = ps + b * NEV + sl * SLEV;
    uint2* ob = bins + b * NEV;

    __shared__ int curs[4][32];
    if (tid < 128) curs[tid >> 5][tid & 31] = cursG[(bid * 4 + (tid >> 5)) * 32 + (tid & 31)];
    __syncthreads();

    for (int i = w * 64 + lane; i < SLEV; i += 256) {
        int p = pb[i];
        int x = xb[i];
        int y = yb[i];
        float t = tb[i];
        int m = (p == 1) ? 0 : 1;
        int bin = m * 16 + (y >> 4);
        int pos = lds_add32(&curs[w][bin], 1);
        ob[pos] = make_uint2((unsigned)(x | (y << 8)), __float_as_uint(t));
    }
}

// =============== event splat (unchanged from R4) ===============
__global__ __launch_bounds__(1024) void k_splat(
    const float* __restrict__ f0, const float* __restrict__ f1,
    const float* __restrict__ f2, const float* __restrict__ f3,
    const uint2* __restrict__ bins, const int* __restrict__ binStart,
    const float* __restrict__ tref,
    u64* __restrict__ fi0P, u64* __restrict__ fi1P,
    float* __restrict__ out) {
    __shared__ u64 acc[8192];   // 64 KB
    __shared__ float red[16];

    int tid = threadIdx.x;
    int bid = blockIdx.x;
    int b = bid & 7;
    int rm = bid >> 3;
    int m = rm & 1;
    int role = rm >> 1;
    int bm = b * 2 + m;

    int fi, row0 = 0, nrows, lo, hi, slice = 0, nslice = 1, mode;
    if (role < 8)       { fi = 0; mode = 0; slice = role;      nslice = 8; nrows = 32; lo = 0; hi = 15; }
    else if (role < 12) { fi = 1; mode = 0; slice = role - 8;  nslice = 4; nrows = 64; lo = 0; hi = 15; }
    else if (role < 20) { int c = role - 12; fi = 2; mode = 1; row0 = 16 * c; nrows = 16;
                          lo = max(0, 2 * c - 1); hi = min(15, 2 * c + 2); }
    else                { int c = role - 20; fi = 3; mode = 1; row0 = 16 * c; nrows = 16;
                          lo = max(0, c - 1); hi = min(15, c + 1); }

    int W = 32 << fi;
    int sh = 3 - fi;
    int planeN = (fi == 0) ? 1024 : (fi == 1) ? 4096 : nrows * W;
    int used = (fi == 0) ? 8192 : 2 * planeN;
    int rowEnd = row0 + nrows;
    float Wm1 = (float)(W - 1);

    const float* flow = (fi == 0) ? f0 : (fi == 1) ? f1 : (fi == 2) ? f2 : f3;
    const float* fxp = flow + (size_t)b * 2 * W * W;
    const float* fyp = fxp + W * W;

    for (int i = tid; i < used; i += 1024) acc[i] = 0ULL;
    __syncthreads();

    float trF = tref[b * 4 + m * 2 + 0];
    float trB = tref[b * 4 + m * 2 + 1];

    int s0 = binStart[b * 33 + m * 16 + lo];
    int e0 = binStart[b * 33 + m * 16 + hi + 1];
    const uint2* eb = bins + b * NEV;

    int rep = (fi == 0) ? (((tid >> 4) & 3) * 2048) : 0;

    for (int i = s0 + slice * 1024 + tid; i < e0; i += nslice * 1024) {
        uint2 ev = eb[i];
        int x = ev.x & 255;
        int y = (ev.x >> 8) & 255;
        float t = __uint_as_float(ev.y);
        int xi = x >> sh, yi = y >> sh;
        float fx = fxp[yi * W + xi];
        float fy = fyp[yi * W + xi];
        float tF = trF - t + F32EPS;
        float tB = trB - t - F32EPS;
        #pragma unroll
        for (int dir = 0; dir < 2; ++dir) {
            float t_ = dir ? tB : tF;
            float x_ = fminf(fmaxf((float)xi + t_ * fx, 0.0f), Wm1);
            float y_ = fminf(fmaxf((float)yi + t_ * fy, 0.0f), Wm1);
            float x0f = floorf(x_), y0f = floorf(y_);
            float x0w = x_ - x0f, x1w = 1.0f - x0w;
            float y0w = y_ - y0f, y1w = 1.0f - y0w;
            int x0i = (int)x0f, y0i = (int)y0f;
            int x1i = min(x0i + 1, W - 1);
            int y1i = min(y0i + 1, W - 1);
            u64 Pa = (1ULL << 32) | (u64)(unsigned)(x0w * y0w * t * SCALE);
            u64 Pb = (1ULL << 32) | (u64)(unsigned)(x1w * y0w * t * SCALE);
            u64 Pc = (1ULL << 32) | (u64)(unsigned)(x0w * y1w * t * SCALE);
            u64 Pd = (1ULL << 32) | (u64)(unsigned)(x1w * y1w * t * SCALE);
            int base = rep + dir * planeN;
            if (mode == 0) {
                int r1 = base + y1i * W;
                int r0 = base + y0i * W;
                lds_add64(&acc[r1 + x1i], Pa);
                lds_add64(&acc[r1 + x0i], Pb);
                lds_add64(&acc[r0 + x1i], Pc);
                lds_add64(&acc[r0 + x0i], Pd);
            } else {
                if (y1i >= row0 && y1i < rowEnd) {
                    int r = base + (y1i - row0) * W;
                    lds_add64(&acc[r + x1i], Pa);
                    lds_add64(&acc[r + x0i], Pb);
                }
                if (y0i >= row0 && y0i < rowEnd) {
                    int r = base + (y0i - row0) * W;
                    lds_add64(&acc[r + x1i], Pc);
                    lds_add64(&acc[r + x0i], Pd);
                }
            }
        }
    }
    __syncthreads();

    if (mode == 0) {
        if (fi == 0) {
            for (int j = tid; j < 2048; j += 1024)
                fi0P[(bm * 8 + slice) * 2048 + j] =
                    acc[j] + acc[j + 2048] + acc[j + 4096] + acc[j + 6144];
        } else {
            for (int j = tid; j < 8192; j += 1024)
                fi1P[(bm * 4 + slice) * 8192 + j] = acc[j];
        }
        return;
    }

    float s = 0.0f;
    for (int j = tid; j < used; j += 1024) {
        u64 v = acc[j];
        float num = (float)(unsigned)(v & 0xffffffffULL) * INV_SCALE;
        float den = (float)(unsigned)(v >> 32);
        float r = num / (den + F32EPS);
        s += sqrtf(r * r + 1e-6f);
    }
    for (int o = 32; o > 0; o >>= 1) s += __shfl_down(s, o, 64);
    if ((tid & 63) == 0) red[tid >> 6] = s;
    __syncthreads();
    if (tid == 0) {
        float tot = 0.0f;
        for (int w2 = 0; w2 < 16; ++w2) tot += red[w2];
        atomicAdd(out, tot);
    }
}

// =============== merge fi0/fi1 partials -> loss terms ===============
__global__ __launch_bounds__(256) void k_merge(const u64* __restrict__ fi0P,
                                               const u64* __restrict__ fi1P,
                                               float* __restrict__ out) {
    int idx = blockIdx.x * 256 + threadIdx.x;   // < 163840
    u64 v = 0;
    if (idx < 32768) {
        int bm = idx >> 11, j = idx & 2047;
        const u64* p = fi0P + (bm * 8) * 2048 + j;
        #pragma unroll
        for (int s = 0; s < 8; ++s) v += p[s * 2048];
    } else {
        int r = idx - 32768;
        int bm = r >> 13, j = r & 8191;
        const u64* p = fi1P + (bm * 4) * 8192 + j;
        #pragma unroll
        for (int s = 0; s < 4; ++s) v += p[s * 8192];
    }
    float num = (float)(unsigned)(v & 0xffffffffULL) * INV_SCALE;
    float den = (float)(unsigned)(v >> 32);
    float r = num / (den + F32EPS);
    float s = sqrtf(r * r + 1e-6f);
    for (int o = 32; o > 0; o >>= 1) s += __shfl_down(s, o, 64);
    __shared__ float red[4];
    if ((threadIdx.x & 63) == 0) red[threadIdx.x >> 6] = s;
    __syncthreads();
    if (threadIdx.x == 0)
        atomicAdd(out, red[0] + red[1] + red[2] + red[3]);
}

// =============== weight decay + smoothness ===============
__global__ __launch_bounds__(256) void k_misc(
    const float* __restrict__ params, int nP,
    const float* __restrict__ f0, const float* __restrict__ f1,
    const float* __restrict__ f2, const float* __restrict__ f3,
    float* __restrict__ out) {
    float s = 0.0f;
    int gstride = gridDim.x * blockDim.x;
    int gtid = blockIdx.x * blockDim.x + threadIdx.x;

    int n4 = nP >> 2;
    const float4* p4 = (const float4*)params;
    float w = 0.0f;
    for (int i = gtid; i < n4; i += gstride) {
        float4 v = p4[i];
        w += v.x * v.x + v.y * v.y + v.z * v.z + v.w * v.w;
    }
    if (gtid == 0) for (int i = n4 * 4; i < nP; ++i) w += params[i] * params[i];
    s += w * 5e-5f;

    const int nTot = 1392640;
    for (int idx = gtid; idx < nTot; idx += gstride) {
        int fi, off, logW;
        if (idx < 16384)       { fi = 0; off = 0;      logW = 5; }
        else if (idx < 81920)  { fi = 1; off = 16384;  logW = 6; }
        else if (idx < 344064) { fi = 2; off = 81920;  logW = 7; }
        else                   { fi = 3; off = 344064; logW = 8; }
        const float* f = (fi == 0) ? f0 : (fi == 1) ? f1 : (fi == 2) ? f2 : f3;
        int W = 1 << logW;
        int local = idx - off;
        int x = local & (W - 1);
        int y = (local >> logW) & (W - 1);
        float c_lr = 6.25f / (float)(16 * W * (W - 1));
        float c_dd = 6.25f / (float)(16 * (W - 1) * (W - 1));
        float v = f[local];
        bool xok = x < W - 1;
        bool yok = y < W - 1;
        float vr = xok ? f[local + 1] : 0.0f;
        float vd = yok ? f[local + W] : 0.0f;
        if (xok) { float d = vr - v; s += c_lr * __powf(d * d + 1e-6f, 0.45f); }
        if (yok) { float d = vd - v; s += c_lr * __powf(d * d + 1e-6f, 0.45f); }
        if (xok && yok) {
            float d1 = f[local + W + 1] - v;
            s += c_dd * __powf(d1 * d1 + 1e-6f, 0.45f);
            float d2 = vr - vd;
            s += c_dd * __powf(d2 * d2 + 1e-6f, 0.45f);
        }
    }

    for (int o = 32; o > 0; o >>= 1) s += __shfl_down(s, o, 64);
    __shared__ float red[4];
    if ((threadIdx.x & 63) == 0) red[threadIdx.x >> 6] = s;
    __syncthreads();
    if (threadIdx.x == 0)
        atomicAdd(out, red[0] + red[1] + red[2] + red[3]);
}

extern "C" void kernel_launch(void* const* d_in, const int* in_sizes, int n_in,
                              void* d_out, int out_size, void* d_ws, size_t ws_size,
                              hipStream_t stream) {
    const float* f0 = (const float*)d_in[0];
    const float* f1 = (const float*)d_in[1];
    const float* f2 = (const float*)d_in[2];
    const float* f3 = (const float*)d_in[3];
    const int*   xs = (const int*)d_in[4];
    const int*   ys = (const int*)d_in[5];
    const float* ts = (const float*)d_in[6];
    const int*   ps = (const int*)d_in[7];
    const float* params = (const float*)d_in[10];
    float* out = (float*)d_out;

    char* ws = (char*)d_ws;
    uint2* bins     = (uint2*)ws;
    int*   binStart = (int*)(ws + OFF_BINSTART);
    float* tref     = (float*)(ws + OFF_TREF);
    u64*   fi0P     = (u64*)(ws + OFF_FI0P);
    u64*   fi1P     = (u64*)(ws + OFF_FI1P);
    int*   histG    = (int*)(ws + OFF_HISTG);
    int*   cursG    = (int*)(ws + OFF_CURSG);
    int*   mmG      = (int*)(ws + OFF_MMG);

    hipLaunchKernelGGL(k_hist, dim3(NB * NSL), dim3(256), 0, stream, ys, ps, histG, mmG);
    hipLaunchKernelGGL(k_scan, dim3(1), dim3(256), 0, stream,
                       histG, mmG, ts, cursG, binStart, tref, out);
    hipLaunchKernelGGL(k_scatter, dim3(NB * NSL), dim3(256), 0, stream,
                       xs, ys, ts, ps, cursG, bins);
    hipLaunchKernelGGL(k_splat, dim3(576), dim3(1024), 0, stream,
                       f0, f1, f2, f3, bins, binStart, tref, fi0P, fi1P, out);
    hipLaunchKernelGGL(k_merge, dim3(640), dim3(256), 0, stream, fi0P, fi1P, out);
    hipLaunchKernelGGL(k_misc, dim3(1024), dim3(256), 0, stream,
                       params, in_sizes[10], f0, f1, f2, f3, out);
}